// Round 16
// baseline (181.475 us; speedup 1.0000x reference)
//
#include <hip/hip_runtime.h>
#include <math.h>

// B=2, T=2048, DIM=1024, H=16, HD=64. Inputs fp32, output fp32.
// R11-R26 history: attn rebuilt (Vimg, VALU L-row, counted-vmcnt 3-parity
// pipeline, XCD swizzle, K=16 PV, direct bf16 out); GEMM pipelined with
// LDS-bounce epilogue; prep fused into gemm1's epilogue. 223 -> 180us.
// R27: gemm k-loop LDS bank conflicts. SQ_LDS_BANK_CONFLICT = 3.1M per gemm
// dispatch (attn = 0): fragment reads at (row*64 + quad*16)B collapse to 8
// bank-groups x 8 lanes = 8-way conflict (~5us/CU of serialized LDS).
// Fix (T2, rule #21 both-sides): slot (r,c) stores data chunk c^((r>>1)&3);
// write side pre-swizzles the GLOBAL source per-lane (LDS dest stays
// DMA-linear per m173); read side XORs quad with ((col>>1)&3) (row terms
// wm,i*16 reduce to 0 mod 4). 2 lanes/bank-group = free. Both gemms gain.

typedef unsigned short u16;
typedef __attribute__((ext_vector_type(8))) short short8;
typedef __attribute__((ext_vector_type(4))) short short4v;
typedef __attribute__((ext_vector_type(4))) float f32x4;
typedef __attribute__((ext_vector_type(16))) float f32x16;

#define T_SEQ 2048

#if __has_builtin(__builtin_amdgcn_exp2f)
#define EXP2(x) __builtin_amdgcn_exp2f(x)
#else
#define EXP2(x) exp2f(x)
#endif

__device__ __forceinline__ float b2f(u16 u) {
    union { unsigned int i; float f; } x; x.i = ((unsigned int)u) << 16; return x.f;
}
__device__ __forceinline__ u16 f2b(float f) {
    union { float f; unsigned int i; } x; x.f = f;
    return (u16)((x.i + 0x7FFFu + ((x.i >> 16) & 1u)) >> 16);  // RNE
}
__device__ __forceinline__ void gl_lds16(const u16* g, u16* l) {
    __builtin_amdgcn_global_load_lds(
        (const __attribute__((address_space(1))) unsigned int*)g,
        (__attribute__((address_space(3))) unsigned int*)l, 16, 0, 0);
}
// pack 2 fp32 -> 1 u32 of 2 bf16 (truncation; tiny bias, verified absmax ok)
__device__ __forceinline__ unsigned int packpair(float a, float b) {
    union { float f; unsigned int u; } xa, xb; xa.f = a; xb.f = b;
    return (xa.u >> 16) | (xb.u & 0xffff0000u);
}

// ---------------------------------------------------------------------------
// Fused setup: [0,4096) cast x->bf16; [4096,7168) transpose Wqkv;
// [7168,8192) transpose Wout; [8192,8704) rope table.
// ---------------------------------------------------------------------------
__global__ __launch_bounds__(256) void setup_kernel(
    const float* __restrict__ x, const float* __restrict__ Wqkv,
    const float* __restrict__ Wout, u16* __restrict__ xb,
    u16* __restrict__ WqkvT, u16* __restrict__ WoutT,
    float* __restrict__ costab, float* __restrict__ sintab)
{
    const int bid = blockIdx.x;
    const int tid = threadIdx.x;

    if (bid < 4096) {
        int i = (bid * 256 + tid) * 4;
        float4 v = *(const float4*)(x + i);
        ushort4 w;
        w.x = f2b(v.x); w.y = f2b(v.y); w.z = f2b(v.z); w.w = f2b(v.w);
        *(ushort4*)(xb + i) = w;
        return;
    }
    if (bid < 8192) {
        const float* in; u16* out; int R, Cn, bx, by;
        if (bid < 7168) { in = Wqkv; out = WqkvT; R = 1024; Cn = 3072;
                          int id = bid - 4096; bx = id % 96; by = id / 96; }
        else            { in = Wout; out = WoutT; R = 1024; Cn = 1024;
                          int id = bid - 7168; bx = id & 31; by = id >> 5; }
        __shared__ u16 tile[32][33];
        const int tx = tid & 31, ty = tid >> 5;
        const int r0 = by * 32, c0 = bx * 32;
#pragma unroll
        for (int rr = ty; rr < 32; rr += 8)
            tile[tx][rr] = f2b(in[(size_t)(r0 + rr) * Cn + c0 + tx]);
        __syncthreads();
#pragma unroll
        for (int rr = ty; rr < 32; rr += 8)
            out[(size_t)(c0 + rr) * R + r0 + tx] = tile[rr][tx];
        return;
    }
    {
        int idx = (bid - 8192) * 256 + tid;
        int t = idx >> 6, d = idx & 63;
        const float nl32 = -0.28782313662425576f;   // -ln(10000)/32
        float f = __expf((float)(d & 31) * nl32);
        float s, c;
        __sincosf((float)t * f, &s, &c);
        costab[idx] = c; sintab[idx] = s;
    }
}

// ---------------------------------------------------------------------------
// MFMA GEMM, counted-vmcnt 3-parity pipeline + R27 LDS chunk swizzle.
// OBF=0: fp32 out direct. OBF=1: bf16 out via LDS-bounce coalesced epilogue.
// OBF=2: fused QKV epilogue (Q/K rope -> Qb/Kb; V -> Vimg permute).
// ---------------------------------------------------------------------------
template<int OBF>
__global__ __launch_bounds__(256) void gemm_bt_mfma(
    const u16* __restrict__ A, const u16* __restrict__ Bt,
    void* __restrict__ Cv, const float* __restrict__ bias,
    int M, int N, int K,
    const float* __restrict__ ctab, const float* __restrict__ stab,
    u16* __restrict__ Qb, u16* __restrict__ Kb, u16* __restrict__ Vimg)
{
    __shared__ u16 sbuf[24576];   // 48 KB: As parities [0,12288), Bs [12288,24576)
    u16* const As0 = sbuf;
    u16* const Bs0 = sbuf + 12288;

    const int tid = threadIdx.x;
    const int wave = tid >> 6, lane = tid & 63;
    const int col = lane & 15, quad = lane >> 4;
    const int wm = (wave & 1) * 64, wn = (wave >> 1) * 64;
    const int m0 = blockIdx.y * 128, n0 = blockIdx.x * 128;

    f32x4 acc[4][4];
#pragma unroll
    for (int i = 0; i < 4; ++i)
#pragma unroll
        for (int j = 0; j < 4; ++j) acc[i][j] = f32x4{0.f, 0.f, 0.f, 0.f};

    // R27 swizzle, write side: thread's LDS slot (r = c>>2, c_slot = c&3)
    // must hold data chunk c_slot ^ ((r>>1)&3) -> permute the GLOBAL source
    // chunk; LDS dest stays DMA-linear (tid*16B).
    const int c1 = tid, c2 = tid + 256;
    const int ch1 = (c1 & 3) ^ ((c1 >> 3) & 3);
    const int ch2 = (c2 & 3) ^ ((c2 >> 3) & 3);
    const u16* a1 = A + (size_t)(m0 + (c1 >> 2)) * K + ch1 * 8;
    const u16* a2 = A + (size_t)(m0 + (c2 >> 2)) * K + ch2 * 8;
    const u16* b1 = Bt + (size_t)(n0 + (c1 >> 2)) * K + ch1 * 8;
    const u16* b2 = Bt + (size_t)(n0 + (c2 >> 2)) * K + ch2 * 8;
    const int l1 = c1 * 8, l2 = c2 * 8;

#define GST(p, ks) do { const int k0_ = (ks) * 32;                            \
        gl_lds16(a1 + k0_, As0 + (p) * 4096 + l1);                            \
        gl_lds16(a2 + k0_, As0 + (p) * 4096 + l2);                            \
        gl_lds16(b1 + k0_, Bs0 + (p) * 4096 + l1);                            \
        gl_lds16(b2 + k0_, Bs0 + (p) * 4096 + l2);                            \
    } while (0)

    const int NK = K >> 5;
    // prologue: k-steps 0,1 in flight (8 DMAs/wave)
    GST(0, 0);
    GST(1, 1);

    // R27 swizzle, read side: data chunk q of row r lives at slot q^((r>>1)&3);
    // for rows wm+i*16+col the row term reduces to (col>>1)&3 (wm,i*16 = 0 mod 4).
    const int qsw = (quad ^ ((col >> 1) & 3)) * 8;

    int cur = 0, prv = 2;
    for (int ks = 0; ks < NK; ++ks) {
        // own k-step's 4 DMAs landed (oldest); next step's 4 stay in flight
        if (ks < NK - 1) asm volatile("s_waitcnt vmcnt(4)" ::: "memory");
        else             asm volatile("s_waitcnt vmcnt(0)" ::: "memory");
        __builtin_amdgcn_s_barrier();
        asm volatile("" ::: "memory");          // compiler fence
        __builtin_amdgcn_sched_barrier(0);      // rule #18: pin MIR scheduler

        // (1) read-first: pull fragments from parity cur (swizzled chunk)
        short8 af[4], bfr[4];
        const u16* Ap = As0 + cur * 4096;
        const u16* Bp = Bs0 + cur * 4096;
#pragma unroll
        for (int i = 0; i < 4; ++i) {
            af[i]  = *(const short8*)&Ap[(wm + i * 16 + col) * 32 + qsw];
            bfr[i] = *(const short8*)&Bp[(wn + i * 16 + col) * 32 + qsw];
        }

        // (2) stage k-step ks+2 into parity prv (freed by this barrier)
        if (ks < NK - 2) GST(prv, ks + 2);

        // (3) register-only MFMA
        __builtin_amdgcn_s_setprio(1);
#pragma unroll
        for (int i = 0; i < 4; ++i)
#pragma unroll
            for (int j = 0; j < 4; ++j)
                acc[i][j] = __builtin_amdgcn_mfma_f32_16x16x32_bf16(
                    af[i], bfr[j], acc[i][j], 0, 0, 0);
        __builtin_amdgcn_s_setprio(0);

        prv = cur;
        cur = (cur == 2) ? 0 : cur + 1;
    }
#undef GST

    if (OBF == 0) {
        // fp32 out: direct stores (64B per 16 lanes, line-friendly) + bias
#pragma unroll
        for (int j = 0; j < 4; ++j) {
            int n = n0 + wn + j * 16 + col;
            float bv = bias ? bias[n] : 0.f;
#pragma unroll
            for (int i = 0; i < 4; ++i) {
                int mbase = m0 + wm + i * 16 + quad * 4;
#pragma unroll
                for (int r = 0; r < 4; ++r)
                    ((float*)Cv)[(size_t)(mbase + r) * N + n] = acc[i][j][r] + bv;
            }
        }
        return;
    }

    // OBF 1/2: bounce acc through LDS ([128][136] u16; 272B stride = 17*16
    // keeps b128 aligned and breaks power-of-2 bank aliasing).
    __syncthreads();
    u16* Cs = sbuf;   // 128*136*2 = 34816 B of the 48 KB
#pragma unroll
    for (int j = 0; j < 4; ++j) {
        const int cl = wn + j * 16 + col;
        const float bv = (OBF == 1 && bias) ? bias[n0 + cl] : 0.f;
#pragma unroll
        for (int i = 0; i < 4; ++i) {
            const int rl = wm + i * 16 + quad * 4;
#pragma unroll
            for (int r = 0; r < 4; ++r)
                Cs[(rl + r) * 136 + cl] = f2b(acc[i][j][r] + bv);
        }
    }
    __syncthreads();

    if (OBF == 1) {
        // plain bf16 row-major out: thread t owns row=t>>1, half=t&1 (128B)
        const int row = tid >> 1, half = tid & 1;
        const u16* src = Cs + row * 136 + half * 64;
        u16* dst = (u16*)Cv + (size_t)(m0 + row) * N + n0 + half * 64;
#pragma unroll
        for (int s = 0; s < 8; ++s)
            *(short8*)(dst + s * 8) = *(const short8*)(src + s * 8);
        return;
    }

    // OBF == 2: fused QKV routing epilogue
    if (n0 < 2048) {
        // Q or K tile: thread owns one full head-row (64 contiguous d)
        const int row = tid >> 1, half = tid & 1;
        const int tt = m0 + row;
        const int b = tt >> 11, t = tt & 2047;
        const int gcol = n0 + half * 64;
        const int isQ = (gcol < 1024) ? 1 : 0;
        const int h = (isQ ? gcol : (gcol - 1024)) >> 6;
        const float sc = isQ ? 0.18033688011112042f : 1.f;   // 0.125*log2(e)
        const u16* src = Cs + row * 136 + half * 64;
        u16* dst = (isQ ? Qb : Kb) + ((size_t)((b * 16 + h) * T_SEQ + t)) * 64;
        const float* cp = ctab + (size_t)t * 64;
        const float* sp = stab + (size_t)t * 64;
#pragma unroll
        for (int c4 = 0; c4 < 4; ++c4) {
            short8 v0 = *(const short8*)(src + c4 * 16);
            short8 v1 = *(const short8*)(src + c4 * 16 + 8);
            float f[16], ct4[16], st4[16];
#pragma unroll
            for (int jj = 0; jj < 8; ++jj) {
                f[jj] = b2f((u16)v0[jj]); f[8 + jj] = b2f((u16)v1[jj]);
            }
#pragma unroll
            for (int jj = 0; jj < 16; jj += 4) {
                *(float4*)&ct4[jj] = *(const float4*)(cp + c4 * 16 + jj);
                *(float4*)&st4[jj] = *(const float4*)(sp + c4 * 16 + jj);
            }
            u16 o[16];
#pragma unroll
            for (int i2 = 0; i2 < 8; ++i2) {
                float e = f[2 * i2], od = f[2 * i2 + 1];
                o[2 * i2]     = f2b((e * ct4[2 * i2]      - od * st4[2 * i2]) * sc);
                o[2 * i2 + 1] = f2b((od * ct4[2 * i2 + 1] + e  * st4[2 * i2 + 1]) * sc);
            }
            *(short8*)(dst + c4 * 16)     = *(short8*)&o[0];
            *(short8*)(dst + c4 * 16 + 8) = *(short8*)&o[8];
        }
    } else {
        // V tile: prep's Vimg permutation with Vls := Cs (rows = 4 key-panels
        // of 32 tokens; cols = 2 heads x 64 d). Per (panel, head): each of
        // 256 threads gathers 8 u16 and writes one short8 to its slot.
        const int b = m0 >> 11;
        const int h0 = (n0 - 2048) >> 6;
        const int ktb = (m0 & 2047) >> 5;
        const int m_ = (tid >> 7) & 1;
        const int db = (tid >> 6) & 1;
        const int h2 = (tid >> 5) & 1;
        const int dv = tid & 31;
        const int k0v = m_ * 16 + h2 * 8;
#pragma unroll
        for (int ph = 0; ph < 8; ++ph) {
            const int panel = ph >> 1, hh = ph & 1;
            const int bh = b * 16 + h0 + hh;
            const int dcol = hh * 64 + db * 32 + dv;
            u16 o[8];
#pragma unroll
            for (int jj = 0; jj < 8; ++jj)
                o[jj] = Cs[(panel * 32 + k0v + jj) * 136 + dcol];
            u16* dst = Vimg + ((size_t)(bh * 64 + ktb + panel)) * 2048 + tid * 8;
            *(short8*)dst = *(short8*)&o[0];
        }
    }
}

// ---------------------------------------------------------------------------
// MFMA flash attention (R24 body): counted-vmcnt 3-parity pipeline, 64-key
// rounds (2 tiles/round, 32 rounds), K=16 PV via permlane32_swap, grid 512
// XCD-swizzled, direct bf16 epilogue -> aob.
// ---------------------------------------------------------------------------
__global__ __launch_bounds__(256, 2) void attn32_kernel(
    const u16* __restrict__ Qb, const u16* __restrict__ Kb,
    const u16* __restrict__ Vimg, u16* __restrict__ aob)
{
    __shared__ u16 Kbuf[3][2][2048];   // [parity][half][tile]  24 KB
    __shared__ u16 Vbuf[3][2][2048];   // 24 KB

    const int tid = threadIdx.x;
    const int wave = tid >> 6, lane = tid & 63;
    const int qcol = lane & 31;
    const int hi = lane >> 5;

    const int bid = blockIdx.x;
    const int lbid = (bid & 7) * 64 + (bid >> 3);
    const int bh = lbid >> 4;
    const int qblk = lbid & 15;
    const int qrow0 = qblk * 128 + wave * 32;

    // Q B-frags (32x32x16): lane(n=q, hi): Q[q][c*16 + hi*8 + j]
    short8 qa[4];
    {
        const u16* qp = Qb + ((size_t)(bh * T_SEQ + qrow0 + qcol)) * 64 + hi * 8;
#pragma unroll
        for (int c = 0; c < 4; ++c) qa[c] = *(const short8*)(qp + c * 16);
    }

    f32x16 O0, O1;
#pragma unroll
    for (int i = 0; i < 16; ++i) { O0[i] = 0.f; O1[i] = 0.f; }
    float Lacc = 0.f;

    const u16* kg_ptr = Kb + ((size_t)bh * T_SEQ + qcol) * 64 + wave * 16 + hi * 8;
    const u16* vg_ptr = Vimg + ((size_t)bh * 64) * 2048 + tid * 8;

#define STAGE2(p, rr) do {                                                    \
        gl_lds16(kg_ptr + (size_t)(2 * (rr))     * 2048, &Kbuf[p][0][tid * 8]);\
        gl_lds16(kg_ptr + (size_t)(2 * (rr) + 1) * 2048, &Kbuf[p][1][tid * 8]);\
        gl_lds16(vg_ptr + (size_t)(2 * (rr))     * 2048, &Vbuf[p][0][tid * 8]);\
        gl_lds16(vg_ptr + (size_t)(2 * (rr) + 1) * 2048, &Vbuf[p][1][tid * 8]);\
    } while (0)

    // prologue: rounds 0,1 in flight (8 DMAs/wave)
    STAGE2(0, 0);
    STAGE2(1, 1);

    int cur = 0, prv = 2;
    for (int r = 0; r < 32; ++r) {
        if (r < 31) asm volatile("s_waitcnt vmcnt(4)" ::: "memory");
        else        asm volatile("s_waitcnt vmcnt(0)" ::: "memory");
        __builtin_amdgcn_s_barrier();
        asm volatile("" ::: "memory");          // compiler fence
        __builtin_amdgcn_sched_barrier(0);      // rule #18

        // (1) read-first: both halves' K/V fragments into registers
        short8 kf[2][4], vA[2][4];
#pragma unroll
        for (int half = 0; half < 2; ++half) {
#pragma unroll
            for (int f = 0; f < 4; ++f)
                kf[half][f] = *(const short8*)&Kbuf[cur][half][(f * 64 + lane) * 8];
#pragma unroll
            for (int rg = 0; rg < 4; ++rg)
                vA[half][rg] = *(const short8*)&Vbuf[cur][half][rg * 512 + lane * 8];
        }

        // (2) stage round r+2 into parity prv (freed by this barrier)
        if (r < 30) STAGE2(prv, r + 2);

        // (3) QK both halves back-to-back
        f32x16 sT0, sT1;
#pragma unroll
        for (int ii = 0; ii < 16; ++ii) { sT0[ii] = 0.f; sT1[ii] = 0.f; }
        __builtin_amdgcn_s_setprio(1);
#pragma unroll
        for (int c = 0; c < 4; ++c)
            sT0 = __builtin_amdgcn_mfma_f32_32x32x16_bf16(kf[0][c], qa[c], sT0, 0, 0, 0);
#pragma unroll
        for (int c = 0; c < 4; ++c)
            sT1 = __builtin_amdgcn_mfma_f32_32x32x16_bf16(kf[1][c], qa[c], sT1, 0, 0, 0);
        __builtin_amdgcn_s_setprio(0);

        // half 0: exp/pack (VALU) then PV (MFMA)
        {
            float pe[16];
#pragma unroll
            for (int ii = 0; ii < 16; ++ii) pe[ii] = EXP2(sT0[ii]);
#pragma unroll
            for (int g = 0; g < 4; ++g)
                Lacc += (pe[4 * g + 0] + pe[4 * g + 1]) +
                        (pe[4 * g + 2] + pe[4 * g + 3]);
            unsigned int W0 = packpair(pe[0],  pe[1]);
            unsigned int W1 = packpair(pe[2],  pe[3]);
            unsigned int W2 = packpair(pe[4],  pe[5]);
            unsigned int W3 = packpair(pe[6],  pe[7]);
            unsigned int W4 = packpair(pe[8],  pe[9]);
            unsigned int W5 = packpair(pe[10], pe[11]);
            unsigned int W6 = packpair(pe[12], pe[13]);
            unsigned int W7 = packpair(pe[14], pe[15]);
            asm volatile("v_permlane32_swap_b32 %0, %1" : "+v"(W0), "+v"(W2));
            asm volatile("v_permlane32_swap_b32 %0, %1" : "+v"(W1), "+v"(W3));
            asm volatile("v_permlane32_swap_b32 %0, %1" : "+v"(W4), "+v"(W6));
            asm volatile("v_permlane32_swap_b32 %0, %1" : "+v"(W5), "+v"(W7));
            union FU { unsigned int u[4]; short8 s; } f0, f1;
            f0.u[0] = W0; f0.u[1] = W1; f0.u[2] = W2; f0.u[3] = W3;
            f1.u[0] = W4; f1.u[1] = W5; f1.u[2] = W6; f1.u[3] = W7;
            __builtin_amdgcn_s_setprio(1);
            O0 = __builtin_amdgcn_mfma_f32_32x32x16_bf16(vA[0][0], f0.s, O0, 0, 0, 0);
            O1 = __builtin_amdgcn_mfma_f32_32x32x16_bf16(vA[0][1], f0.s, O1, 0, 0, 0);
            O0 = __builtin_amdgcn_mfma_f32_32x32x16_bf16(vA[0][2], f1.s, O0, 0, 0, 0);
            O1 = __builtin_amdgcn_mfma_f32_32x32x16_bf16(vA[0][3], f1.s, O1, 0, 0, 0);
            __builtin_amdgcn_s_setprio(0);
        }
        // half 1
        {
            float pe[16];
#pragma unroll
            for (int ii = 0; ii < 16; ++ii) pe[ii] = EXP2(sT1[ii]);
#pragma unroll
            for (int g = 0; g < 4; ++g)
                Lacc += (pe[4 * g + 0] + pe[4 * g + 1]) +
                        (pe[4 * g + 2] + pe[4 * g + 3]);
            unsigned int W0 = packpair(pe[0],  pe[1]);
            unsigned int W1 = packpair(pe[2],  pe[3]);
            unsigned int W2 = packpair(pe[4],  pe[5]);
            unsigned int W3 = packpair(pe[6],  pe[7]);
            unsigned int W4 = packpair(pe[8],  pe[9]);
            unsigned int W5 = packpair(pe[10], pe[11]);
            unsigned int W6 = packpair(pe[12], pe[13]);
            unsigned int W7 = packpair(pe[14], pe[15]);
            asm volatile("v_permlane32_swap_b32 %0, %1" : "+v"(W0), "+v"(W2));
            asm volatile("v_permlane32_swap_b32 %0, %1" : "+v"(W1), "+v"(W3));
            asm volatile("v_permlane32_swap_b32 %0, %1" : "+v"(W4), "+v"(W6));
            asm volatile("v_permlane32_swap_b32 %0, %1" : "+v"(W5), "+v"(W7));
            union FU { unsigned int u[4]; short8 s; } f0, f1;
            f0.u[0] = W0; f0.u[1] = W1; f0.u[2] = W2; f0.u[3] = W3;
            f1.u[0] = W4; f1.u[1] = W5; f1.u[2] = W6; f1.u[3] = W7;
            __builtin_amdgcn_s_setprio(1);
            O0 = __builtin_amdgcn_mfma_f32_32x32x16_bf16(vA[1][0], f0.s, O0, 0, 0, 0);
            O1 = __builtin_amdgcn_mfma_f32_32x32x16_bf16(vA[1][1], f0.s, O1, 0, 0, 0);
            O0 = __builtin_amdgcn_mfma_f32_32x32x16_bf16(vA[1][2], f1.s, O0, 0, 0, 0);
            O1 = __builtin_amdgcn_mfma_f32_32x32x16_bf16(vA[1][3], f1.s, O1, 0, 0, 0);
            __builtin_amdgcn_s_setprio(0);
        }

        prv = cur;
        cur = (cur == 2) ? 0 : cur + 1;
    }
#undef STAGE2

    float Lq = Lacc + __shfl(Lacc, lane ^ 32);
    float inv = 1.f / Lq;

    const int b = bh >> 4, h = bh & 15;
    u16* ab = aob + ((size_t)(b * T_SEQ + qrow0 + qcol)) * 1024 + h * 64;
#pragma unroll
    for (int g2 = 0; g2 < 4; ++g2) {
        int dd = g2 * 8 + hi * 4;
        ushort4 w0, w1;
        w0.x = f2b(O0[4 * g2 + 0] * inv); w0.y = f2b(O0[4 * g2 + 1] * inv);
        w0.z = f2b(O0[4 * g2 + 2] * inv); w0.w = f2b(O0[4 * g2 + 3] * inv);
        w1.x = f2b(O1[4 * g2 + 0] * inv); w1.y = f2b(O1[4 * g2 + 1] * inv);
        w1.z = f2b(O1[4 * g2 + 2] * inv); w1.w = f2b(O1[4 * g2 + 3] * inv);
        *(ushort4*)(ab + dd)      = w0;
        *(ushort4*)(ab + 32 + dd) = w1;
    }
}

// ---------------------------------------------------------------------------
extern "C" void kernel_launch(void* const* d_in, const int* in_sizes, int n_in,
                              void* d_out, int out_size, void* d_ws, size_t ws_size,
                              hipStream_t stream)
{
    const float* x    = (const float*)d_in[0];
    const float* Wqkv = (const float*)d_in[1];
    const float* Wout = (const float*)d_in[2];
    const float* bout = (const float*)d_in[3];
    float* out = (float*)d_out;

    char* w = (char*)d_ws;
    u16* xb      = (u16*)(w + 25165824);        //  8,388,608  (dead after gemm1)
    u16* WqkvT   = (u16*)(w + 33554432);        //  6,291,456  (dead after gemm1)
    u16* WoutT   = (u16*)(w + 39845888);        //  2,097,152
    u16* aob     = (u16*)(w + 41943040);        //  8,388,608
    u16* Qb      = (u16*)(w + 50331648);        //  8,388,608
    u16* Kb      = (u16*)(w + 58720256);        //  8,388,608
    u16* Vimg    = (u16*)(w + 67108864);        //  8,388,608
    float* ctab  = (float*)(w + 75497472);      //    524,288
    float* stab  = (float*)(w + 76021760);      //    524,288

    dim3 blk(256);
    setup_kernel<<<dim3(8704), blk, 0, stream>>>(x, Wqkv, Wout, xb, WqkvT, WoutT, ctab, stab);
    gemm_bt_mfma<2><<<dim3(24, 32), blk, 0, stream>>>(
        xb, WqkvT, nullptr, nullptr, 4096, 3072, 1024, ctab, stab, Qb, Kb, Vimg);
    attn32_kernel<<<dim3(512), blk, 0, stream>>>(Qb, Kb, Vimg, aob);
    gemm_bt_mfma<0><<<dim3(8, 32), blk, 0, stream>>>(
        aob, WoutT, out, bout, 4096, 1024, 1024, nullptr, nullptr, nullptr, nullptr, nullptr);
}